// Round 3
// baseline (293.903 us; speedup 1.0000x reference)
//
#include <hip/hip_runtime.h>

#define NLAT 361
#define NLON 720
#define LMAX 360
#define MMAX 361

// ---------------- kernel 1: folded DFT, on-the-fly trig ----------------
// X[bc,k,m] = sum_{n=0}^{360} fc(n,m)*xe[n] + i * fs(n,m)*xo[n]
// xe[n]=x[n]+x[720-n] (n=1..359), edges n=0,360 use xbv=0 (fs=0 there).
// Writes chunk-local Xt: [m-mb][k][bc] complex -> 4x float4 per (m,k).
__global__ __launch_bounds__(128) void k_dft(const float* __restrict__ x,
                                             float* __restrict__ xt,
                                             int mb, int mc) {
    const int k   = blockIdx.x;            // 0..360 latitude
    const int tid = threadIdx.x;           // 0..127
    const float* __restrict__ xk = x + k * NLON;

    const float kAng = 8.72664625997164788e-3f;   // 2*pi/720 (= output scale too)

    int  mm[3]; bool vld[3]; int tacc[3];
#pragma unroll
    for (int s = 0; s < 3; ++s) {
        int mo = tid + s * 128;
        vld[s]  = (mo < mc);
        mm[s]   = mb + (vld[s] ? mo : 0);
        tacc[s] = 0;                       // (n*m) % 720, incremental & exact
    }

    float aRe[3][8], aIm[3][8];
#pragma unroll
    for (int s = 0; s < 3; ++s)
#pragma unroll
        for (int b = 0; b < 8; ++b) { aRe[s][b] = 0.f; aIm[s][b] = 0.f; }

    for (int n = 0; n < NLAT; ++n) {
        const bool edge = (n == 0) || (n == 360);
        const int  nb   = edge ? 0 : (NLON - n);
        float xe[8], xo[8];
#pragma unroll
        for (int b = 0; b < 8; ++b) {
            float xa  = xk[b * (NLAT * NLON) + n];    // wave-uniform
            float xbv = edge ? 0.f : xk[b * (NLAT * NLON) + nb];
            xe[b] = xa + xbv;
            xo[b] = xa - xbv;
        }
        float fc[3], fs[3];
#pragma unroll
        for (int s = 0; s < 3; ++s) {
            float sn, cs;
            __sincosf((float)tacc[s] * kAng, &sn, &cs);
            fc[s] = kAng * cs;
            fs[s] = -kAng * sn;
            tacc[s] += mm[s];
            if (tacc[s] >= NLON) tacc[s] -= NLON;     // m<720 -> one subtract
        }
#pragma unroll
        for (int s = 0; s < 3; ++s)
#pragma unroll
            for (int b = 0; b < 8; ++b) {
                aRe[s][b] += fc[s] * xe[b];
                aIm[s][b] += fs[s] * xo[b];
            }
    }

    float4* __restrict__ xt4 = (float4*)xt;
#pragma unroll
    for (int s = 0; s < 3; ++s) {
        if (!vld[s]) continue;
        int base = ((mm[s] - mb) * NLAT + k) * 4;
#pragma unroll
        for (int q = 0; q < 4; ++q)
            xt4[base + q] = make_float4(aRe[s][2*q], aIm[s][2*q],
                                        aRe[s][2*q+1], aIm[s][2*q+1]);
    }
}

// ---------------- kernel 2: triangular contraction ----------------
// out[bc,l,m] = sum_k W[m,l,k] * X[bc,k,m]   (zero for l < m)
// block = (mloc, 24-l tile); 192 thr = 32 k-lanes x 6 l-groups; 4 l/thread.
// pairs==1: d_out is interleaved complex (float2). pairs==0: real part only.
__global__ __launch_bounds__(192) void k_contract(const float* __restrict__ W,
                                                  const float* __restrict__ xt,
                                                  float* __restrict__ out,
                                                  int mb, int pairs) {
    const int mloc = blockIdx.x;
    const int m    = mb + mloc;            // global m
    const int lt   = blockIdx.y;           // 0..14
    const int l0   = lt * 24;
    const int tid  = threadIdx.x;

    if (l0 + 23 < m) {                      // whole tile below diagonal -> zeros
        int l = l0 + (tid >> 3), bc = tid & 7;
        int idx = (bc * LMAX + l) * MMAX + m;
        if (pairs) { ((float2*)out)[idx] = make_float2(0.f, 0.f); }
        else       { out[idx] = 0.f; }
        return;
    }

    __shared__ float2 Xs[NLAT * 9];         // stride-9 float2: 2-way alias = free
    const float2* __restrict__ xt2 = (const float2*)xt;
    for (int j = tid; j < NLAT * 8; j += 192) {
        Xs[(j >> 3) * 9 + (j & 7)] = xt2[mloc * (NLAT * 8) + j];
    }
    __syncthreads();

    const int kk = tid & 31, lq = tid >> 5;
    const int lb = l0 + lq * 4;

    float v[64];
#pragma unroll
    for (int i = 0; i < 64; ++i) v[i] = 0.f;

    const float* __restrict__ Wm = W + (size_t)m * (LMAX * NLAT);

    for (int kt = 0; kt < NLAT; kt += 32) {
        int  kq   = kt + kk;
        bool kvld = kq < NLAT;
        int  kc   = kvld ? kq : (NLAT - 1);
        float w0 = Wm[(lb + 0) * NLAT + kc];
        float w1 = Wm[(lb + 1) * NLAT + kc];
        float w2 = Wm[(lb + 2) * NLAT + kc];
        float w3 = Wm[(lb + 3) * NLAT + kc];
        if (!kvld) { w0 = w1 = w2 = w3 = 0.f; }
        float2 xv[8];
#pragma unroll
        for (int b = 0; b < 8; ++b) xv[b] = Xs[kc * 9 + b];
#pragma unroll
        for (int b = 0; b < 8; ++b) {
            v[ 0 + b*2 + 0] += w0 * xv[b].x;  v[ 0 + b*2 + 1] += w0 * xv[b].y;
            v[16 + b*2 + 0] += w1 * xv[b].x;  v[16 + b*2 + 1] += w1 * xv[b].y;
            v[32 + b*2 + 0] += w2 * xv[b].x;  v[32 + b*2 + 1] += w2 * xv[b].y;
            v[48 + b*2 + 0] += w3 * xv[b].x;  v[48 + b*2 + 1] += w3 * xv[b].y;
        }
    }

    // split-butterfly reduce over 32 k-lanes; lane kk ends owning O[2kk+p].
    // keep = my half, send = the half my partner owns.
#define RSTEP(MASK, CNT) { const bool hi = (kk & MASK) != 0; \
    _Pragma("unroll") \
    for (int i = 0; i < CNT; ++i) { \
        float keep = hi ? v[i + CNT] : v[i]; \
        float send = hi ? v[i] : v[i + CNT]; \
        v[i] = keep + __shfl_xor(send, MASK); } }
    RSTEP(16, 32)
    RSTEP(8, 16)
    RSTEP(4, 8)
    RSTEP(2, 4)
    RSTEP(1, 2)
#undef RSTEP

    // O index = 2*kk + p ; original layout v[j*16 + bc*2 + p]
    int j  = kk >> 3;
    int bc = kk & 7;
    int l  = l0 + lq * 4 + j;
    float re = v[0], im = v[1];
    if (l < m) { re = 0.f; im = 0.f; }
    int idx = (bc * LMAX + l) * MMAX + m;
    if (pairs) { ((float2*)out)[idx] = make_float2(re, im); }
    else       { out[idx] = re; }
}

extern "C" void kernel_launch(void* const* d_in, const int* in_sizes, int n_in,
                              void* d_out, int out_size, void* d_ws, size_t ws_size,
                              hipStream_t stream) {
    const float* x = (const float*)d_in[0];
    const float* W = (const float*)d_in[1];
    float* ws = (float*)d_ws;

    // Does d_out hold interleaved complex pairs (2 floats per output) or
    // real-part-only (1 float per output)?  Decide from out_size.
    const int n_complex = 8 * LMAX * MMAX;            // 1,039,680
    const int pairs = (out_size >= 2 * n_complex) ? 1 : 0;

    // Xt chunk: per m we need NLAT*8 complex = 23,104 bytes.
    const size_t per_m_bytes = (size_t)NLAT * 8 * 2 * sizeof(float);
    int CM = (int)(ws_size / per_m_bytes);
    if (CM > MMAX) CM = MMAX;
    if (CM < 1)    CM = 1;

    for (int mbase = 0; mbase < MMAX; mbase += CM) {
        int mc = MMAX - mbase;
        if (mc > CM) mc = CM;
        k_dft<<<dim3(NLAT), dim3(128), 0, stream>>>(x, ws, mbase, mc);
        k_contract<<<dim3(mc, 15), dim3(192), 0, stream>>>(W, ws, (float*)d_out,
                                                           mbase, pairs);
    }
}

// Round 4
// 172.500 us; speedup vs baseline: 1.7038x; 1.7038x over previous
//
#include <hip/hip_runtime.h>

#define NLAT 361
#define NLON 720
#define LMAX 360
#define MMAX 361

#define XT_FLOATS  2085136            // 361*361*8*2
#define TAB_FLOAT2 130321             // 361*361 entries (float2 each)

static constexpr double kPId = 3.14159265358979323846;

// ---------------- kernel 0: trig table ----------------
// Ftab[n*361+m] = ( w*s*cos(2*pi*(n*m%720)/720), -w*s*sin(...) ), w=0.5 at n=360
__global__ __launch_bounds__(256) void k_tables(float2* __restrict__ tab) {
    int i = blockIdx.x * 256 + threadIdx.x;
    if (i >= TAB_FLOAT2) return;
    int n = i / MMAX;
    int m = i - n * MMAX;
    int t = (n * m) % NLON;
    double a = (double)t * (2.0 * kPId / (double)NLON);
    double s, c;
    sincos(a, &s, &c);
    double w = (n == 360) ? 0.5 : 1.0;
    double scale = 2.0 * kPId / (double)NLON;
    tab[i] = make_float2((float)(w * scale * c), (float)(-w * scale * s));
}

// ---------------- kernel 1: folded DFT ----------------
// X[bc,k,m] = sum_{n=0}^{360} fc(n,m)*xe[n] + i*fs(n,m)*xo[n]
// xe[n]=x[n]+x[720-n] (pad x[720]=0 handles n=0; n=360 weight baked in table)
// grid: (NLAT, ceil(mc/192)), block 192. Xt layout: [m_local][k][bc] complex.
__global__ __launch_bounds__(192) void k_dft(const float* __restrict__ x,
                                             float* __restrict__ xt,
                                             const float2* __restrict__ tab,
                                             int mb, int mc, int use_tab) {
    const int k    = blockIdx.x;
    const int half = blockIdx.y;
    const int tid  = threadIdx.x;

    __shared__ float  xr[8 * 724];          // raw rows, padded (slot 720..723 = 0)
    __shared__ float2 exo[8 * 361];         // folded even/odd pairs

    // stage raw x rows (coalesced float4)
    {
        const float4* __restrict__ x4 = (const float4*)x;
        for (int j = tid; j < 8 * 180; j += 192) {
            int b = j / 180, q = j - b * 180;
            ((float4*)&xr[b * 724])[q] = x4[(b * NLAT + k) * 180 + q];
        }
        if (tid < 8) ((float4*)&xr[tid * 724])[180] = make_float4(0.f, 0.f, 0.f, 0.f);
    }
    __syncthreads();

    // fold: exo[b*361+n] = {x[n]+x[720-n], x[n]-x[720-n]}  (n=0 -> pad 0)
    for (int j = tid; j < 8 * NLAT; j += 192) {
        int b = j / NLAT, n = j - b * NLAT;
        float xa = xr[b * 724 + n];
        float xbv = xr[b * 724 + (NLON - n)];   // n=0 hits pad (=0)
        exo[j] = make_float2(xa + xbv, xa - xbv);
    }
    __syncthreads();

    const int m_local = half * 192 + tid;
    const bool valid  = (m_local < mc);
    const int  m      = mb + (valid ? m_local : 0);

    float aRe[8], aIm[8];
#pragma unroll
    for (int b = 0; b < 8; ++b) { aRe[b] = 0.f; aIm[b] = 0.f; }

    if (use_tab) {
        const float2* __restrict__ trow = tab + m;
        for (int n = 0; n < NLAT; ++n) {
            float2 f = trow[n * MMAX];          // coalesced across tid
#pragma unroll
            for (int b = 0; b < 8; ++b) {
                float2 e = exo[b * NLAT + n];   // uniform -> broadcast
                aRe[b] += f.x * e.x;
                aIm[b] += f.y * e.y;
            }
        }
    } else {
        const float kAng = 8.72664625997164788e-3f;   // 2*pi/720
        int tacc = 0;
        for (int n = 0; n < NLAT; ++n) {
            float sn, cs;
            __sincosf((float)tacc * kAng, &sn, &cs);
            float wgt = (n == 360) ? 0.5f : 1.0f;
            float fc = wgt * kAng * cs;
            float fs = -wgt * kAng * sn;
            tacc += m;
            if (tacc >= NLON) tacc -= NLON;
#pragma unroll
            for (int b = 0; b < 8; ++b) {
                float2 e = exo[b * NLAT + n];
                aRe[b] += fc * e.x;
                aIm[b] += fs * e.y;
            }
        }
    }

    if (valid) {
        float4* __restrict__ xt4 = (float4*)xt;
        int base = (m_local * NLAT + k) * 4;
#pragma unroll
        for (int q = 0; q < 4; ++q)
            xt4[base + q] = make_float4(aRe[2*q], aIm[2*q], aRe[2*q+1], aIm[2*q+1]);
    }
}

// ---------------- kernel 2: triangular contraction (unchanged) ----------------
__global__ __launch_bounds__(192) void k_contract(const float* __restrict__ W,
                                                  const float* __restrict__ xt,
                                                  float* __restrict__ out,
                                                  int mb, int pairs) {
    const int mloc = blockIdx.x;
    const int m    = mb + mloc;
    const int lt   = blockIdx.y;
    const int l0   = lt * 24;
    const int tid  = threadIdx.x;

    if (l0 + 23 < m) {
        int l = l0 + (tid >> 3), bc = tid & 7;
        int idx = (bc * LMAX + l) * MMAX + m;
        if (pairs) { ((float2*)out)[idx] = make_float2(0.f, 0.f); }
        else       { out[idx] = 0.f; }
        return;
    }

    __shared__ float2 Xs[NLAT * 9];
    const float2* __restrict__ xt2 = (const float2*)xt;
    for (int j = tid; j < NLAT * 8; j += 192) {
        Xs[(j >> 3) * 9 + (j & 7)] = xt2[mloc * (NLAT * 8) + j];
    }
    __syncthreads();

    const int kk = tid & 31, lq = tid >> 5;
    const int lb = l0 + lq * 4;

    float v[64];
#pragma unroll
    for (int i = 0; i < 64; ++i) v[i] = 0.f;

    const float* __restrict__ Wm = W + (size_t)m * (LMAX * NLAT);

    for (int kt = 0; kt < NLAT; kt += 32) {
        int  kq   = kt + kk;
        bool kvld = kq < NLAT;
        int  kc   = kvld ? kq : (NLAT - 1);
        float w0 = Wm[(lb + 0) * NLAT + kc];
        float w1 = Wm[(lb + 1) * NLAT + kc];
        float w2 = Wm[(lb + 2) * NLAT + kc];
        float w3 = Wm[(lb + 3) * NLAT + kc];
        if (!kvld) { w0 = w1 = w2 = w3 = 0.f; }
        float2 xv[8];
#pragma unroll
        for (int b = 0; b < 8; ++b) xv[b] = Xs[kc * 9 + b];
#pragma unroll
        for (int b = 0; b < 8; ++b) {
            v[ 0 + b*2 + 0] += w0 * xv[b].x;  v[ 0 + b*2 + 1] += w0 * xv[b].y;
            v[16 + b*2 + 0] += w1 * xv[b].x;  v[16 + b*2 + 1] += w1 * xv[b].y;
            v[32 + b*2 + 0] += w2 * xv[b].x;  v[32 + b*2 + 1] += w2 * xv[b].y;
            v[48 + b*2 + 0] += w3 * xv[b].x;  v[48 + b*2 + 1] += w3 * xv[b].y;
        }
    }

#define RSTEP(MASK, CNT) { const bool hi = (kk & MASK) != 0; \
    _Pragma("unroll") \
    for (int i = 0; i < CNT; ++i) { \
        float keep = hi ? v[i + CNT] : v[i]; \
        float send = hi ? v[i] : v[i + CNT]; \
        v[i] = keep + __shfl_xor(send, MASK); } }
    RSTEP(16, 32)
    RSTEP(8, 16)
    RSTEP(4, 8)
    RSTEP(2, 4)
    RSTEP(1, 2)
#undef RSTEP

    int j  = kk >> 3;
    int bc = kk & 7;
    int l  = l0 + lq * 4 + j;
    float re = v[0], im = v[1];
    if (l < m) { re = 0.f; im = 0.f; }
    int idx = (bc * LMAX + l) * MMAX + m;
    if (pairs) { ((float2*)out)[idx] = make_float2(re, im); }
    else       { out[idx] = re; }
}

extern "C" void kernel_launch(void* const* d_in, const int* in_sizes, int n_in,
                              void* d_out, int out_size, void* d_ws, size_t ws_size,
                              hipStream_t stream) {
    const float* x = (const float*)d_in[0];
    const float* W = (const float*)d_in[1];
    float* ws = (float*)d_ws;

    const int n_complex = 8 * LMAX * MMAX;
    const int pairs = (out_size >= 2 * n_complex) ? 1 : 0;

    const size_t full_bytes = (size_t)(XT_FLOATS + 2 * TAB_FLOAT2) * sizeof(float);

    if (ws_size >= full_bytes) {
        // full Xt + trig table
        float2* tab = (float2*)(ws + XT_FLOATS);
        k_tables<<<dim3((TAB_FLOAT2 + 255) / 256), dim3(256), 0, stream>>>(tab);
        k_dft<<<dim3(NLAT, (MMAX + 191) / 192), dim3(192), 0, stream>>>(
            x, ws, tab, 0, MMAX, 1);
        k_contract<<<dim3(MMAX, 15), dim3(192), 0, stream>>>(W, ws, (float*)d_out,
                                                             0, pairs);
    } else {
        // chunked, on-the-fly trig
        const size_t per_m_bytes = (size_t)NLAT * 8 * 2 * sizeof(float);
        int CM = (int)(ws_size / per_m_bytes);
        if (CM > MMAX) CM = MMAX;
        if (CM < 1)    CM = 1;
        for (int mbase = 0; mbase < MMAX; mbase += CM) {
            int mc = MMAX - mbase;
            if (mc > CM) mc = CM;
            k_dft<<<dim3(NLAT, (mc + 191) / 192), dim3(192), 0, stream>>>(
                x, ws, nullptr, mbase, mc, 0);
            k_contract<<<dim3(mc, 15), dim3(192), 0, stream>>>(W, ws, (float*)d_out,
                                                               mbase, pairs);
        }
    }
}

// Round 5
// 80.102 us; speedup vs baseline: 3.6691x; 2.1535x over previous
//
#include <hip/hip_runtime.h>

#define NLAT 361
#define NLON 720
#define LMAX 360
#define MMAX 361

#define TAB_FLOAT2 130321             // 361*361

static constexpr double kPId = 3.14159265358979323846;

// ---------------- kernel 0: trig table ----------------
// tab[n*361+m] = ( w*s*cos(2*pi*(n*m%720)/720), -w*s*sin(...) ), w=0.5 at n=360
__global__ __launch_bounds__(256) void k_tables(float2* __restrict__ tab) {
    int i = blockIdx.x * 256 + threadIdx.x;
    if (i >= TAB_FLOAT2) return;
    int n = i / MMAX;
    int m = i - n * MMAX;
    int t = (n * m) % NLON;
    double a = (double)t * (2.0 * kPId / (double)NLON);
    double s, c;
    sincos(a, &s, &c);
    double w = (n == 360) ? 0.5 : 1.0;
    double scale = 2.0 * kPId / (double)NLON;
    tab[i] = make_float2((float)(w * scale * c), (float)(-w * scale * s));
}

// ---------------- kernel 1: folded DFT ----------------
// Re(X)[m,k,b] = sum_n fc(n,m)*xe[n];  (CPLX also Im with fs*xo)
// Xt layout: real: [m_local][k][8 floats]; cplx: [m_local][k][8 x (re,im)]
template<int CPLX>
__global__ __launch_bounds__(192) void k_dft(const float* __restrict__ x,
                                             float* __restrict__ xt,
                                             const float2* __restrict__ tab,
                                             int mb, int mc, int use_tab) {
    const int k    = blockIdx.x;
    const int half = blockIdx.y;
    const int tid  = threadIdx.x;

    __shared__ __align__(16) float  xr[8 * 724];   // raw rows (720 + pad 0)
    __shared__ __align__(16) float2 exo[8 * 362];  // folded pairs, padded stride

    {
        const float4* __restrict__ x4 = (const float4*)x;
        for (int j = tid; j < 8 * 180; j += 192) {
            int b = j / 180, q = j - b * 180;
            ((float4*)&xr[b * 724])[q] = x4[(b * NLAT + k) * 180 + q];
        }
        if (tid < 8) ((float4*)&xr[tid * 724])[180] = make_float4(0.f, 0.f, 0.f, 0.f);
    }
    __syncthreads();

    for (int j = tid; j < 8 * NLAT; j += 192) {
        int b = j / NLAT, n = j - b * NLAT;
        float xa  = xr[b * 724 + n];
        float xbv = xr[b * 724 + (NLON - n)];      // n=0 hits pad (=0)
        exo[b * 362 + n] = make_float2(xa + xbv, xa - xbv);
    }
    __syncthreads();

    const int  m_local = half * 192 + tid;
    const bool valid   = (m_local < mc);
    const int  m       = mb + (valid ? m_local : 0);

    float aRe[8], aIm[8];
#pragma unroll
    for (int b = 0; b < 8; ++b) { aRe[b] = 0.f; aIm[b] = 0.f; }

    if (use_tab) {
        const float2* __restrict__ trow = tab + m;
        float2 f[4];
#pragma unroll
        for (int u = 0; u < 4; ++u) f[u] = trow[u * MMAX];
        for (int t = 0; t < 90; ++t) {             // n = 4t .. 4t+3
            float2 fn[4];
            if (t < 89) {
#pragma unroll
                for (int u = 0; u < 4; ++u) fn[u] = trow[(4 * t + 4 + u) * MMAX];
            }
            const int nb = 4 * t;
#pragma unroll
            for (int b = 0; b < 8; ++b) {
                float4 ea = *(const float4*)&exo[b * 362 + nb];
                float4 eb = *(const float4*)&exo[b * 362 + nb + 2];
                aRe[b] += f[0].x * ea.x + f[1].x * ea.z
                        + f[2].x * eb.x + f[3].x * eb.z;
                if (CPLX)
                    aIm[b] += f[0].y * ea.y + f[1].y * ea.w
                            + f[2].y * eb.y + f[3].y * eb.w;
            }
            if (t < 89) {
#pragma unroll
                for (int u = 0; u < 4; ++u) f[u] = fn[u];
            }
        }
        {   // n = 360
            float2 f3 = trow[360 * MMAX];
#pragma unroll
            for (int b = 0; b < 8; ++b) {
                float2 e = exo[b * 362 + 360];
                aRe[b] += f3.x * e.x;
                if (CPLX) aIm[b] += f3.y * e.y;
            }
        }
    } else {
        const float kAng = 8.72664625997164788e-3f;   // 2*pi/720
        int tacc = 0;
        for (int n = 0; n < NLAT; ++n) {
            float sn, cs;
            __sincosf((float)tacc * kAng, &sn, &cs);
            float wgt = (n == 360) ? 0.5f : 1.0f;
            float fc = wgt * kAng * cs;
            float fs = -wgt * kAng * sn;
            tacc += m;
            if (tacc >= NLON) tacc -= NLON;
#pragma unroll
            for (int b = 0; b < 8; ++b) {
                float2 e = exo[b * 362 + n];
                aRe[b] += fc * e.x;
                if (CPLX) aIm[b] += fs * e.y;
            }
        }
    }

    if (valid) {
        float4* __restrict__ xt4 = (float4*)xt;
        if (CPLX) {
            int base = (m_local * NLAT + k) * 4;
#pragma unroll
            for (int q = 0; q < 4; ++q)
                xt4[base + q] = make_float4(aRe[2*q], aIm[2*q], aRe[2*q+1], aIm[2*q+1]);
        } else {
            int base = (m_local * NLAT + k) * 2;
            xt4[base + 0] = make_float4(aRe[0], aRe[1], aRe[2], aRe[3]);
            xt4[base + 1] = make_float4(aRe[4], aRe[5], aRe[6], aRe[7]);
        }
    }
}

// ---------------- kernel 2: triangular contraction ----------------
// out[bc,l,m] = sum_k W[m,l,k] * X[k,m]   (zero for l < m)
// block 256 = 32 k-lanes x 8 l-groups x 4 l; 32-l tiles; no LDS;
// double-buffered register prefetch of W (+X) keeps loads in flight.
template<int CPLX>
__global__ __launch_bounds__(256) void k_contract(const float* __restrict__ W,
                                                  const float* __restrict__ xt,
                                                  float* __restrict__ out,
                                                  int mb) {
    const int lt   = blockIdx.x;            // 0..11 (fastest -> same-m adjacent)
    const int mloc = blockIdx.y;
    const int m    = mb + mloc;
    const int l0   = lt * 32;
    const int tid  = threadIdx.x;

    if (l0 + 31 < m) {                      // tile fully below diagonal
        int l = l0 + (tid >> 3), bc = tid & 7;
        int idx = (bc * LMAX + l) * MMAX + m;
        if (CPLX) ((float2*)out)[idx] = make_float2(0.f, 0.f);
        else      out[idx] = 0.f;
        return;
    }

    const int kk = tid & 31, lq = tid >> 5; // lq 0..7
    const int lb = l0 + lq * 4;

    int lr[4];
#pragma unroll
    for (int j = 0; j < 4; ++j) lr[j] = (lb + j < LMAX) ? (lb + j) : (LMAX - 1);

    const float* __restrict__ Wm = W + (size_t)m * (LMAX * NLAT);
    const float4* __restrict__ xt4 = (const float4*)xt;
    constexpr int NX = CPLX ? 4 : 2;        // float4s per (m,k)
    constexpr int NV = CPLX ? 64 : 32;

    float v[NV];
#pragma unroll
    for (int i = 0; i < NV; ++i) v[i] = 0.f;

#define CLOAD(T, WV, XV) { \
    int kq = (T) * 32 + kk; \
    int kc = (kq < NLAT) ? kq : (NLAT - 1); \
    _Pragma("unroll") \
    for (int j = 0; j < 4; ++j) WV[j] = Wm[lr[j] * NLAT + kc]; \
    int xb = (mloc * NLAT + kc) * NX; \
    _Pragma("unroll") \
    for (int q = 0; q < NX; ++q) XV[q] = xt4[xb + q]; \
    if (kq >= NLAT) { WV[0] = WV[1] = WV[2] = WV[3] = 0.f; } }

    float  wc[4]; float4 xc[NX];
    CLOAD(0, wc, xc)
#pragma unroll
    for (int t = 0; t < 12; ++t) {
        float  wn[4]; float4 xn[NX];
        if (t < 11) CLOAD(t + 1, wn, xn)
#pragma unroll
        for (int j = 0; j < 4; ++j) {
            float wj = wc[j];
            if (CPLX) {
#pragma unroll
                for (int q = 0; q < 4; ++q) {
                    v[j*16 + (2*q  )*2 + 0] += wj * xc[q].x;
                    v[j*16 + (2*q  )*2 + 1] += wj * xc[q].y;
                    v[j*16 + (2*q+1)*2 + 0] += wj * xc[q].z;
                    v[j*16 + (2*q+1)*2 + 1] += wj * xc[q].w;
                }
            } else {
                v[j*8 + 0] += wj * xc[0].x;  v[j*8 + 1] += wj * xc[0].y;
                v[j*8 + 2] += wj * xc[0].z;  v[j*8 + 3] += wj * xc[0].w;
                v[j*8 + 4] += wj * xc[1].x;  v[j*8 + 5] += wj * xc[1].y;
                v[j*8 + 6] += wj * xc[1].z;  v[j*8 + 7] += wj * xc[1].w;
            }
        }
        if (t < 11) {
#pragma unroll
            for (int j = 0; j < 4; ++j) wc[j] = wn[j];
#pragma unroll
            for (int q = 0; q < NX; ++q) xc[q] = xn[q];
        }
    }
#undef CLOAD

    // split-butterfly over 32 k-lanes
#define RSTEP(MASK, CNT) { const bool hi = (kk & MASK) != 0; \
    _Pragma("unroll") \
    for (int i = 0; i < CNT; ++i) { \
        float keep = hi ? v[i + CNT] : v[i]; \
        float send = hi ? v[i] : v[i + CNT]; \
        v[i] = keep + __shfl_xor(send, MASK); } }
    if (CPLX) {
        RSTEP(16, 32) RSTEP(8, 16) RSTEP(4, 8) RSTEP(2, 4) RSTEP(1, 2)
    } else {
        RSTEP(16, 16) RSTEP(8, 8) RSTEP(4, 4) RSTEP(2, 2) RSTEP(1, 1)
    }
#undef RSTEP

    int j  = kk >> 3;
    int bc = kk & 7;
    int l  = l0 + lq * 4 + j;
    if (l >= LMAX) return;                  // lt=11 tail (l 360..383)
    int idx = (bc * LMAX + l) * MMAX + m;
    if (CPLX) {
        float2 r = make_float2(v[0], v[1]);
        if (l < m) r = make_float2(0.f, 0.f);
        ((float2*)out)[idx] = r;
    } else {
        float r = (l < m) ? 0.f : v[0];
        out[idx] = r;
    }
}

extern "C" void kernel_launch(void* const* d_in, const int* in_sizes, int n_in,
                              void* d_out, int out_size, void* d_ws, size_t ws_size,
                              hipStream_t stream) {
    const float* x = (const float*)d_in[0];
    const float* W = (const float*)d_in[1];
    float* ws = (float*)d_ws;

    const int n_complex = 8 * LMAX * MMAX;            // 1,039,680
    const int cplx = (out_size >= 2 * n_complex) ? 1 : 0;

    const int xs_per_mk   = cplx ? 16 : 8;            // floats per (m,k)
    const size_t xt_floats = (size_t)MMAX * NLAT * xs_per_mk;
    const size_t full_bytes = (xt_floats + 2 * (size_t)TAB_FLOAT2) * sizeof(float);

    if (ws_size >= full_bytes) {
        float2* tab = (float2*)(ws + xt_floats);
        k_tables<<<dim3((TAB_FLOAT2 + 255) / 256), dim3(256), 0, stream>>>(tab);
        if (cplx) {
            k_dft<1><<<dim3(NLAT, 2), dim3(192), 0, stream>>>(x, ws, tab, 0, MMAX, 1);
            k_contract<1><<<dim3(12, MMAX), dim3(256), 0, stream>>>(W, ws, (float*)d_out, 0);
        } else {
            k_dft<0><<<dim3(NLAT, 2), dim3(192), 0, stream>>>(x, ws, tab, 0, MMAX, 1);
            k_contract<0><<<dim3(12, MMAX), dim3(256), 0, stream>>>(W, ws, (float*)d_out, 0);
        }
    } else {
        const size_t per_m_bytes = (size_t)NLAT * xs_per_mk * sizeof(float);
        int CM = (int)(ws_size / per_m_bytes);
        if (CM > MMAX) CM = MMAX;
        if (CM < 1)    CM = 1;
        for (int mbase = 0; mbase < MMAX; mbase += CM) {
            int mc = MMAX - mbase;
            if (mc > CM) mc = CM;
            if (cplx) {
                k_dft<1><<<dim3(NLAT, (mc + 191) / 192), dim3(192), 0, stream>>>(
                    x, ws, nullptr, mbase, mc, 0);
                k_contract<1><<<dim3(12, mc), dim3(256), 0, stream>>>(W, ws, (float*)d_out, mbase);
            } else {
                k_dft<0><<<dim3(NLAT, (mc + 191) / 192), dim3(192), 0, stream>>>(
                    x, ws, nullptr, mbase, mc, 0);
                k_contract<0><<<dim3(12, mc), dim3(256), 0, stream>>>(W, ws, (float*)d_out, mbase);
            }
        }
    }
}